// Round 16
// baseline (253.415 us; speedup 1.0000x reference)
//
#include <hip/hip_runtime.h>
#include <hip/hip_bf16.h>

typedef __bf16 bf16;
typedef bf16 bf16x8 __attribute__((ext_vector_type(8)));
typedef float f32x4 __attribute__((ext_vector_type(4)));

#define EPI_BIAS_RELU      0
#define EPI_BIAS_BF16      1
#define EPI_PLAIN_BF16     2
#define EPI_RESID_BIAS_F32 3

__device__ __forceinline__ void lds_load16(const bf16* g, bf16* l) {
  __builtin_amdgcn_global_load_lds((__attribute__((address_space(1))) void*)g,
                                   (__attribute__((address_space(3))) void*)l,
                                   16, 0, 0);
}

template<int N> __device__ __forceinline__ void vmw() {
  if constexpr (N == 0) asm volatile("s_waitcnt vmcnt(0)" ::: "memory");
  else if constexpr (N == 4) asm volatile("s_waitcnt vmcnt(4)" ::: "memory");
}
__device__ __forceinline__ void barrier() { asm volatile("s_barrier" ::: "memory"); }

// Row-slab XCD mapping (r7-proven). Bijective when (gy*gz)%8==0.
__device__ __forceinline__ void xcd_map(int& bx, int& by, int& z) {
  const int gx = gridDim.x, gy = gridDim.y;
  const int Y8 = (gy * gridDim.z) >> 3;
  const int L = (blockIdx.z * gy + blockIdx.y) * gx + blockIdx.x;
  const int xcd = L & 7, j = L >> 3;
  bx = j % gx;
  const int yy = xcd * Y8 + j / gx;
  by = yy % gy;
  z  = yy / gy;
}

// ====== gemm2s device body: 128x128 tile, BK=64, dbuf 64KB (r11-proven) ======
template<int EPI>
__device__ __forceinline__ void gemm2s_body(
    int bx, int by, int z,
    const bf16* __restrict__ A, const bf16* __restrict__ B,
    void* __restrict__ Cv, const float* __restrict__ bias,
    const bf16* __restrict__ resid,
    int K, int lda, int ldb, int ldc, int ldr, int biasZ,
    long long sAz, long long sBz, long long sCz, long long sRz)
{
  constexpr int BK = 64;
  constexpr int M_REP = 4, NH = 2;

  __shared__ __align__(16) bf16 lA[2][128 * BK];
  __shared__ __align__(16) bf16 lB[2][128 * BK];

  const bf16* Ab = A + (size_t)z * sAz;
  const bf16* Bb = B + (size_t)z * sBz;
  const int row0 = by * 128, col0 = bx * 128;
  const int tid = threadIdx.x, w = tid >> 6, l = tid & 63;
  const int wr = w >> 1, wc = w & 1;

  const int srow = l >> 3, scb = (l & 7) ^ srow;
  const bf16* gA = Ab + (size_t)(row0 + w * 8 + srow) * lda + scb * 8;
  const bf16* gB = Bb + (size_t)(col0 + w * 8 + srow) * ldb + scb * 8;

  auto issueA = [&](int buf, int k0) {
#pragma unroll
    for (int i = 0; i < 4; i++)
      lds_load16(gA + (size_t)(i * 32) * lda + k0,
                 &lA[buf][(i * 32 + w * 8) * BK]);
  };
  auto issueB = [&](int buf, int k0) {
#pragma unroll
    for (int i = 0; i < 4; i++)
      lds_load16(gB + (size_t)(i * 32) * ldb + k0,
                 &lB[buf][(i * 32 + w * 8) * BK]);
  };

  const int fr = l & 15, fq = l >> 4, sw = fr & 7;
  bf16x8 aA[M_REP][2], bB0[NH][2], bB1[NH][2];
  f32x4 acc[M_REP][4] = {};

  auto readAfull = [&](int buf) {
#pragma unroll
    for (int m = 0; m < M_REP; m++) {
      const bf16* base = &lA[buf][(wr * 64 + m * 16 + fr) * BK];
#pragma unroll
      for (int kk = 0; kk < 2; kk++)
        aA[m][kk] = *(const bf16x8*)(base + ((kk * 4 + fq) ^ sw) * 8);
    }
  };
  auto readB = [&](bf16x8 (&dst)[NH][2], int buf, int h) {
#pragma unroll
    for (int nn = 0; nn < NH; nn++) {
      const bf16* base = &lB[buf][(wc * 64 + h * 32 + nn * 16 + fr) * BK];
#pragma unroll
      for (int kk = 0; kk < 2; kk++)
        dst[nn][kk] = *(const bf16x8*)(base + ((kk * 4 + fq) ^ sw) * 8);
    }
  };
  auto quad16 = [&](const bf16x8 (&b)[NH][2], int nBase) {
    __builtin_amdgcn_s_setprio(1);
#pragma unroll
    for (int kk = 0; kk < 2; kk++)
#pragma unroll
      for (int m = 0; m < M_REP; m++)
#pragma unroll
        for (int nh = 0; nh < NH; nh++)
          acc[m][nBase + nh] = __builtin_amdgcn_mfma_f32_16x16x32_bf16(
              aA[m][kk], b[nh][kk], acc[m][nBase + nh], 0, 0, 0);
    __builtin_amdgcn_s_setprio(0);
  };

  const int NT = K / BK;
  issueA(0, 0); issueB(0, 0); issueA(1, BK);
  vmw<4>();
  barrier();

  for (int t = 0; t < NT; t++) {
    const int cur = t & 1, nxt = cur ^ 1;
    const bool s1 = (t + 1 < NT), s2 = (t + 2 < NT);
    readAfull(cur);
    readB(bB0, cur, 0);
    if (s1) issueB(nxt, (t + 1) * BK);
    barrier();
    quad16(bB0, 0);
    barrier();
    readB(bB1, cur, 1);
    if (s2) { issueA(cur, (t + 2) * BK); vmw<4>(); }
    else vmw<0>();
    barrier();
    quad16(bB1, NH);
    barrier();
  }

  const float* bz = bias ? bias + (size_t)z * biasZ : nullptr;
#pragma unroll
  for (int m = 0; m < M_REP; m++) {
#pragma unroll
    for (int n = 0; n < 4; n++) {
      const int col = col0 + wc * 64 + n * 16 + fr;
#pragma unroll
      for (int j = 0; j < 4; j++) {
        const int rrow = row0 + wr * 64 + m * 16 + fq * 4 + j;
        const float val = acc[m][n][j];
        if constexpr (EPI == EPI_PLAIN_BF16) {
          bf16* Cp = (bf16*)Cv + (size_t)z * sCz;
          Cp[(size_t)rrow * ldc + col] = (bf16)val;
        } else if constexpr (EPI == EPI_BIAS_BF16) {
          bf16* Cp = (bf16*)Cv + (size_t)z * sCz;
          Cp[(size_t)rrow * ldc + col] = (bf16)(val + bz[col]);
        } else if constexpr (EPI == EPI_BIAS_RELU) {
          bf16* Cp = (bf16*)Cv;
          Cp[(size_t)rrow * ldc + col] = (bf16)fmaxf(val + bz[col], 0.f);
        } else {  // EPI_RESID_BIAS_F32
          float* Cp = (float*)Cv + (size_t)z * sCz;
          const bf16* Rp = resid + (size_t)z * sRz;
          Cp[(size_t)rrow * ldc + col] =
              val + (float)Rp[(size_t)rrow * ldr + col] + bz[col];
        }
      }
    }
  }
}

template<int EPI>
__global__ __launch_bounds__(256, 2)
void gemm2s(const bf16* __restrict__ A, const bf16* __restrict__ B,
            void* __restrict__ Cv, const float* __restrict__ bias,
            const bf16* __restrict__ resid,
            int K, int lda, int ldb, int ldc, int ldr, int biasZ,
            long long sAz, long long sBz, long long sCz, long long sRz)
{
  int bx, by, z;
  xcd_map(bx, by, z);
  gemm2s_body<EPI>(bx, by, z, A, B, Cv, bias, resid,
                   K, lda, ldb, ldc, ldr, biasZ, sAz, sBz, sCz, sRz);
}

// ====== FUSED dispatch: WW-precompute (128 blocks) + G1 (1024 blocks) ======
// blocks [0,128):   z=0 WcT = wkT @ wqT^T ; z=1 Wvo = wob @ wvT^T
//                   sub-grid (8,8,2); 128%8==0 keeps real-XCD == L&7.
// blocks [128,1152): G1 h1 = relu(x @ w1^T + b1), sub-grid (16,64,1).
__global__ __launch_bounds__(256, 2)
void g1ww(const bf16* __restrict__ xb, const bf16* __restrict__ w1b,
          bf16* __restrict__ h1, const float* __restrict__ b1,
          const bf16* __restrict__ T4, bf16* __restrict__ WW)
{
  const int gb = blockIdx.x;
  if (gb < 128) {  // WW precompute: gx=8, gy=8, gz=2 -> Y8=2
    const int L = gb, xcd = L & 7, j = L >> 3;
    const int bx = j & 7, yy = xcd * 2 + (j >> 3);
    const int by = yy & 7, z = yy >> 3;
    gemm2s_body<EPI_PLAIN_BF16>(bx, by, z,
        T4 + (2 << 20), T4, WW, nullptr, nullptr,
        1024, 1024, 1024, 1024, 0, 0, 1 << 20, 1 << 20, 1 << 20, 0);
  } else {  // G1: gx=16, gy=64, gz=1 -> Y8=8
    const int L = gb - 128, xcd = L & 7, j = L >> 3;
    const int bx = j & 15, by = xcd * 8 + (j >> 4);
    gemm2s_body<EPI_BIAS_RELU>(bx, by, 0,
        xb, w1b, h1, b1, nullptr,
        1024, 1024, 1024, 2048, 0, 0, 0, 0, 0, 0);
  }
}

// ===== FUSED prep kernel (7936 blocks; matvecs first = latency overlap) =====
__global__ __launch_bounds__(256)
void cast_fused(const float* __restrict__ x,  const float* __restrict__ w1,
                const float* __restrict__ w2, const float* __restrict__ wq,
                const float* __restrict__ wk, const float* __restrict__ wv,
                const float* __restrict__ wo, const float* __restrict__ bq,
                const float* __restrict__ bv,
                bf16* __restrict__ xb, bf16* __restrict__ w1b,
                bf16* __restrict__ w2b, bf16* __restrict__ T4,
                float* __restrict__ bcbvo) {
  const int b = blockIdx.x, tid = threadIdx.x;
  if (b < 512) {  // matvecs: one wave per output
    const int wv_ = tid >> 6, ln = tid & 63;
    float acc = 0.f;
    if (b < 256) {
      const int e = b * 4 + wv_;
#pragma unroll
      for (int i = 0; i < 16; i++) {
        const int f = ln + i * 64;
        acc += bq[f] * 0.03125f * wk[(size_t)f * 1024 + e];
      }
      for (int o = 32; o; o >>= 1) acc += __shfl_xor(acc, o);
      if (ln == 0) bcbvo[e] = acc;
    } else {
      const int o = (b - 256) * 4 + wv_;
#pragma unroll
      for (int i = 0; i < 16; i++) {
        const int f = ln + i * 64;
        acc += wo[(size_t)o * 1024 + f] * bv[f];
      }
      for (int oo = 32; oo; oo >>= 1) acc += __shfl_xor(acc, oo);
      if (ln == 0) bcbvo[1024 + o] = acc;
    }
    return;
  }
  if (b < 7168) {  // straight casts
    const float* src; bf16* dst; int base;
    if (b < 4608)      { src = x;  dst = xb;        base = b - 512; }
    else if (b < 5632) { src = w1; dst = w1b;       base = b - 4608; }
    else if (b < 6656) { src = w2; dst = w2b;       base = b - 5632; }
    else               { src = wo; dst = T4 + (3 << 20); base = b - 6656; }
    const int i = base * 256 + tid;
    const float4* p = (const float4*)src;
    float4 a = p[2 * i], c = p[2 * i + 1];
    bf16x8 o8;
    o8[0] = (bf16)a.x; o8[1] = (bf16)a.y; o8[2] = (bf16)a.z; o8[3] = (bf16)a.w;
    o8[4] = (bf16)c.x; o8[5] = (bf16)c.y; o8[6] = (bf16)c.z; o8[7] = (bf16)c.w;
    ((bf16x8*)dst)[i] = o8;
    return;
  }
  // transpose-cast 64x64 tiles ([64][73] pad: 2-way max bank alias)
  __shared__ bf16 t[64][73];
  const float* src; bf16* dst; int tt; float scale = 1.f;
  if (b < 7424)      { src = wq; dst = T4;              tt = b - 7168; scale = 0.03125f; }
  else if (b < 7680) { src = wv; dst = T4 + (1 << 20);  tt = b - 7424; }
  else               { src = wk; dst = T4 + (2 << 20);  tt = b - 7680; }
  const int ty = tt >> 4, tx = tt & 15;
  const float* ib = src + (size_t)(ty * 64) * 1024 + tx * 64;
#pragma unroll
  for (int p = 0; p < 2; p++) {
    int r = p * 32 + tid / 8, cc = (tid % 8) * 8;
    float4 a = *(const float4*)(ib + (size_t)r * 1024 + cc);
    float4 d = *(const float4*)(ib + (size_t)r * 1024 + cc + 4);
    t[r][cc + 0] = (bf16)(a.x * scale); t[r][cc + 1] = (bf16)(a.y * scale);
    t[r][cc + 2] = (bf16)(a.z * scale); t[r][cc + 3] = (bf16)(a.w * scale);
    t[r][cc + 4] = (bf16)(d.x * scale); t[r][cc + 5] = (bf16)(d.y * scale);
    t[r][cc + 6] = (bf16)(d.z * scale); t[r][cc + 7] = (bf16)(d.w * scale);
  }
  __syncthreads();
#pragma unroll
  for (int p = 0; p < 2; p++) {
    int r = p * 32 + tid / 8, cc = (tid % 8) * 8;
    bf16x8 o;
#pragma unroll
    for (int j = 0; j < 8; j++) o[j] = t[cc + j][r];
    *(bf16x8*)(dst + (size_t)(tx * 64 + r) * 1024 + ty * 64 + cc) = o;
  }
}

// ===== FUSED softmax + g-transpose (10240 blocks) =====
__global__ __launch_bounds__(256)
void smT(bf16* __restrict__ S, const bf16* __restrict__ g,
         bf16* __restrict__ gT) {
  __shared__ float redm[4], reds[4];
  __shared__ bf16 t[64][73];
  const int b = blockIdx.x, tid = threadIdx.x;
  if (b < 8192) {
    const size_t row = b;
    const int wv_ = tid >> 6, ln = tid & 63;
    bf16x8 v8 = ((const bf16x8*)(S + row * 2048))[tid];
    float v[8];
#pragma unroll
    for (int j = 0; j < 8; j++) v[j] = (float)v8[j];
    float m = v[0];
#pragma unroll
    for (int j = 1; j < 8; j++) m = fmaxf(m, v[j]);
    for (int o = 32; o; o >>= 1) m = fmaxf(m, __shfl_xor(m, o));
    if (ln == 0) redm[wv_] = m;
    __syncthreads();
    m = fmaxf(fmaxf(redm[0], redm[1]), fmaxf(redm[2], redm[3]));
    float e[8], s = 0.f;
#pragma unroll
    for (int j = 0; j < 8; j++) { e[j] = __expf(v[j] - m); s += e[j]; }
    for (int o = 32; o; o >>= 1) s += __shfl_xor(s, o);
    if (ln == 0) reds[wv_] = s;
    __syncthreads();
    s = reds[0] + reds[1] + reds[2] + reds[3];
    const float inv = 1.f / s;
    bf16x8 o8;
#pragma unroll
    for (int j = 0; j < 8; j++) o8[j] = (bf16)(e[j] * inv);
    ((bf16x8*)(S + row * 2048))[tid] = o8;
    return;
  }
  const int tt = b - 8192;
  const int z = tt >> 9, rem = tt & 511;
  const int ty = rem >> 4, tx = rem & 15;
  const bf16* ib = g + (size_t)z * 2048 * 1024 + (size_t)(ty * 64) * 1024 + tx * 64;
  bf16* ob = gT + (size_t)z * 1024 * 2048;
#pragma unroll
  for (int p = 0; p < 2; p++) {
    int r = p * 32 + tid / 8, cc = (tid % 8) * 8;
    bf16x8 vv = *(const bf16x8*)(ib + (size_t)r * 1024 + cc);
#pragma unroll
    for (int j = 0; j < 8; j++) t[r][cc + j] = vv[j];
  }
  __syncthreads();
#pragma unroll
  for (int p = 0; p < 2; p++) {
    int r = p * 32 + tid / 8, cc = (tid % 8) * 8;
    bf16x8 o;
#pragma unroll
    for (int j = 0; j < 8; j++) o[j] = t[cc + j][r];
    *(bf16x8*)(ob + (size_t)(tx * 64 + r) * 2048 + ty * 64 + cc) = o;
  }
}

extern "C" void kernel_launch(void* const* d_in, const int* in_sizes, int n_in,
                              void* d_out, int out_size, void* d_ws, size_t ws_size,
                              hipStream_t stream) {
  const float* x  = (const float*)d_in[0];
  const float* w1 = (const float*)d_in[1];
  const float* b1 = (const float*)d_in[2];
  const float* w2 = (const float*)d_in[3];
  const float* b2 = (const float*)d_in[4];
  const float* wq = (const float*)d_in[5];
  const float* bq = (const float*)d_in[6];
  const float* wk = (const float*)d_in[7];
  const float* bk = (const float*)d_in[8];  // drops out: softmax row-invariant
  const float* wv = (const float*)d_in[9];
  const float* bv = (const float*)d_in[10];
  const float* wo = (const float*)d_in[11];
  const float* bo = (const float*)d_in[12];
  float* out = (float*)d_out;
  (void)bk;

  char* ws = (char*)d_ws;
  const size_t MB = 1024ull * 1024ull;
  if (ws_size < 130 * MB) return;

  bf16* w1b = (bf16*)(ws + 0 * MB);    // 4 MB
  bf16* w2b = (bf16*)(ws + 4 * MB);    // 4 MB
  bf16* T4  = (bf16*)(ws + 14 * MB);   // 8 MB: [wqT][wvT][wkT][wob]
  bf16* WW  = (bf16*)(ws + 22 * MB);   // 4 MB: [WcT][Wvo]
  float* bcbvo = (float*)(ws + 26 * MB);  // 8 KB: [bc 1024][bvo 1024]
  bf16* xb  = (bf16*)(ws + 27 * MB);   // 16 MB, dead after G1
  bf16* h1  = (bf16*)(ws + 43 * MB);   // 32 MB, dead after G2
  bf16* h   = (bf16*)(ws + 75 * MB);   // 16 MB, alive thru S'
  bf16* hq  = (bf16*)(ws + 91 * MB);   // 16 MB, dead after S'
  bf16* g   = (bf16*)(ws + 107 * MB);  // 16 MB, alive thru Pg (resid)
  bf16* S   = (bf16*)(ws + 43 * MB);   // 32 MB over dead h1 (softmax in-place)
  bf16* gT  = (bf16*)(ws + 27 * MB);   // 16 MB over dead xb

  // 1. fused prep: matvecs (front) + casts + weight transpose-casts
  cast_fused<<<7936, 256, 0, stream>>>(x, w1, w2, wq, wk, wv, wo, bq, bv,
                                       xb, w1b, w2b, T4, bcbvo);
  // 2. fused: WW precompute (128 blk) + G1 (1024 blk)
  g1ww<<<1152, 256, 0, stream>>>(xb, w1b, h1, b1, T4, WW);
  // 3. G2: h = relu(h1 @ w2^T + b2)   M=8192 N=1024 K=2048
  gemm2s<EPI_BIAS_RELU><<<dim3(8, 64, 1), 256, 0, stream>>>(
      h1, w2b, h, b2, nullptr, 2048, 2048, 2048, 1024, 0, 0, 0, 0, 0, 0);
  // 4. z-batched: z=0 hq = h @ WcT^T + bc ; z=1 g = h @ Wvo^T + bvo
  gemm2s<EPI_BIAS_BF16><<<dim3(8, 64, 2), 256, 0, stream>>>(
      h, WW, hq, bcbvo, nullptr, 1024, 1024, 1024, 1024, 0, 1024,
      0, 1 << 20, 8LL << 20, 0);
  // 5. S' = hq @ h^T (z=4; differs from ref by softmax-invariant row const)
  gemm2s<EPI_PLAIN_BF16><<<dim3(16, 16, 4), 256, 0, stream>>>(
      hq, h, S, nullptr, nullptr, 1024, 1024, 1024, 2048, 0, 0,
      2048LL * 1024, 2048LL * 1024, 2048LL * 2048, 0);
  // 6. fused: P = softmax(S) in place  ∥  gT = transpose(g)
  smT<<<10240, 256, 0, stream>>>(S, g, gT);
  // 7. out = P @ gT^T + g + bo (f32)   M=2048 N=1024 K=2048, z=4
  gemm2s<EPI_RESID_BIAS_F32><<<dim3(8, 16, 4), 256, 0, stream>>>(
      S, gT, out, bo, g, 2048, 2048, 2048, 1024, 1024, 0,
      2048LL * 2048, 2048LL * 1024, 2048LL * 1024, 2048LL * 1024);
}

// Round 17
// 239.233 us; speedup vs baseline: 1.0593x; 1.0593x over previous
//
#include <hip/hip_runtime.h>
#include <hip/hip_bf16.h>

typedef __bf16 bf16;
typedef bf16 bf16x8 __attribute__((ext_vector_type(8)));
typedef float f32x4 __attribute__((ext_vector_type(4)));

#define EPI_BIAS_RELU      0
#define EPI_BIAS_BF16      1
#define EPI_PLAIN_BF16     2
#define EPI_RESID_BIAS_F32 3

__device__ __forceinline__ void lds_load16(const bf16* g, bf16* l) {
  __builtin_amdgcn_global_load_lds((__attribute__((address_space(1))) void*)g,
                                   (__attribute__((address_space(3))) void*)l,
                                   16, 0, 0);
}

template<int N> __device__ __forceinline__ void vmw() {
  if constexpr (N == 0) asm volatile("s_waitcnt vmcnt(0)" ::: "memory");
  else if constexpr (N == 4) asm volatile("s_waitcnt vmcnt(4)" ::: "memory");
}
__device__ __forceinline__ void barrier() { asm volatile("s_barrier" ::: "memory"); }

// Row-slab XCD mapping (r7-proven). Bijective when (gy*gz)%8==0.
__device__ __forceinline__ void xcd_map(int& bx, int& by, int& z) {
  const int gx = gridDim.x, gy = gridDim.y;
  const int Y8 = (gy * gridDim.z) >> 3;
  const int L = (blockIdx.z * gy + blockIdx.y) * gx + blockIdx.x;
  const int xcd = L & 7, j = L >> 3;
  bx = j % gx;
  const int yy = xcd * Y8 + j / gx;
  by = yy % gy;
  z  = yy / gy;
}

// ====== gemm2s device body: 128x128 tile, BK=64, dbuf (r11-proven) ======
// LDS is PASSED IN (lA/lB = 2x 128*64 bf16 each) so multi-branch fused
// kernels share one 64KB allocation (r16 lesson: per-branch __shared__ sums).
template<int EPI>
__device__ __forceinline__ void gemm2s_body(
    bf16* __restrict__ lA, bf16* __restrict__ lB,
    int bx, int by, int z,
    const bf16* __restrict__ A, const bf16* __restrict__ B,
    void* __restrict__ Cv, const float* __restrict__ bias,
    const bf16* __restrict__ resid,
    int K, int lda, int ldb, int ldc, int ldr, int biasZ,
    long long sAz, long long sBz, long long sCz, long long sRz)
{
  constexpr int BK = 64;
  constexpr int M_REP = 4, NH = 2;
  constexpr int HB = 128 * BK;  // half-buffer stride

  const bf16* Ab = A + (size_t)z * sAz;
  const bf16* Bb = B + (size_t)z * sBz;
  const int row0 = by * 128, col0 = bx * 128;
  const int tid = threadIdx.x, w = tid >> 6, l = tid & 63;
  const int wr = w >> 1, wc = w & 1;

  const int srow = l >> 3, scb = (l & 7) ^ srow;
  const bf16* gA = Ab + (size_t)(row0 + w * 8 + srow) * lda + scb * 8;
  const bf16* gB = Bb + (size_t)(col0 + w * 8 + srow) * ldb + scb * 8;

  auto issueA = [&](int buf, int k0) {
#pragma unroll
    for (int i = 0; i < 4; i++)
      lds_load16(gA + (size_t)(i * 32) * lda + k0,
                 lA + buf * HB + (i * 32 + w * 8) * BK);
  };
  auto issueB = [&](int buf, int k0) {
#pragma unroll
    for (int i = 0; i < 4; i++)
      lds_load16(gB + (size_t)(i * 32) * ldb + k0,
                 lB + buf * HB + (i * 32 + w * 8) * BK);
  };

  const int fr = l & 15, fq = l >> 4, sw = fr & 7;
  bf16x8 aA[M_REP][2], bB0[NH][2], bB1[NH][2];
  f32x4 acc[M_REP][4] = {};

  auto readAfull = [&](int buf) {
#pragma unroll
    for (int m = 0; m < M_REP; m++) {
      const bf16* base = lA + buf * HB + (wr * 64 + m * 16 + fr) * BK;
#pragma unroll
      for (int kk = 0; kk < 2; kk++)
        aA[m][kk] = *(const bf16x8*)(base + ((kk * 4 + fq) ^ sw) * 8);
    }
  };
  auto readB = [&](bf16x8 (&dst)[NH][2], int buf, int h) {
#pragma unroll
    for (int nn = 0; nn < NH; nn++) {
      const bf16* base = lB + buf * HB + (wc * 64 + h * 32 + nn * 16 + fr) * BK;
#pragma unroll
      for (int kk = 0; kk < 2; kk++)
        dst[nn][kk] = *(const bf16x8*)(base + ((kk * 4 + fq) ^ sw) * 8);
    }
  };
  auto quad16 = [&](const bf16x8 (&b)[NH][2], int nBase) {
    __builtin_amdgcn_s_setprio(1);
#pragma unroll
    for (int kk = 0; kk < 2; kk++)
#pragma unroll
      for (int m = 0; m < M_REP; m++)
#pragma unroll
        for (int nh = 0; nh < NH; nh++)
          acc[m][nBase + nh] = __builtin_amdgcn_mfma_f32_16x16x32_bf16(
              aA[m][kk], b[nh][kk], acc[m][nBase + nh], 0, 0, 0);
    __builtin_amdgcn_s_setprio(0);
  };

  const int NT = K / BK;
  issueA(0, 0); issueB(0, 0); issueA(1, BK);
  vmw<4>();
  barrier();

  for (int t = 0; t < NT; t++) {
    const int cur = t & 1, nxt = cur ^ 1;
    const bool s1 = (t + 1 < NT), s2 = (t + 2 < NT);
    readAfull(cur);
    readB(bB0, cur, 0);
    if (s1) issueB(nxt, (t + 1) * BK);
    barrier();
    quad16(bB0, 0);
    barrier();
    readB(bB1, cur, 1);
    if (s2) { issueA(cur, (t + 2) * BK); vmw<4>(); }
    else vmw<0>();
    barrier();
    quad16(bB1, NH);
    barrier();
  }

  const float* bz = bias ? bias + (size_t)z * biasZ : nullptr;
#pragma unroll
  for (int m = 0; m < M_REP; m++) {
#pragma unroll
    for (int n = 0; n < 4; n++) {
      const int col = col0 + wc * 64 + n * 16 + fr;
#pragma unroll
      for (int j = 0; j < 4; j++) {
        const int rrow = row0 + wr * 64 + m * 16 + fq * 4 + j;
        const float val = acc[m][n][j];
        if constexpr (EPI == EPI_PLAIN_BF16) {
          bf16* Cp = (bf16*)Cv + (size_t)z * sCz;
          Cp[(size_t)rrow * ldc + col] = (bf16)val;
        } else if constexpr (EPI == EPI_BIAS_BF16) {
          bf16* Cp = (bf16*)Cv + (size_t)z * sCz;
          Cp[(size_t)rrow * ldc + col] = (bf16)(val + bz[col]);
        } else if constexpr (EPI == EPI_BIAS_RELU) {
          bf16* Cp = (bf16*)Cv;
          Cp[(size_t)rrow * ldc + col] = (bf16)fmaxf(val + bz[col], 0.f);
        } else {  // EPI_RESID_BIAS_F32
          float* Cp = (float*)Cv + (size_t)z * sCz;
          const bf16* Rp = resid + (size_t)z * sRz;
          Cp[(size_t)rrow * ldc + col] =
              val + (float)Rp[(size_t)rrow * ldr + col] + bz[col];
        }
      }
    }
  }
}

template<int EPI>
__global__ __launch_bounds__(256, 2)
void gemm2s(const bf16* __restrict__ A, const bf16* __restrict__ B,
            void* __restrict__ Cv, const float* __restrict__ bias,
            const bf16* __restrict__ resid,
            int K, int lda, int ldb, int ldc, int ldr, int biasZ,
            long long sAz, long long sBz, long long sCz, long long sRz)
{
  __shared__ __align__(16) bf16 lA[2 * 128 * 64];
  __shared__ __align__(16) bf16 lB[2 * 128 * 64];
  int bx, by, z;
  xcd_map(bx, by, z);
  gemm2s_body<EPI>(lA, lB, bx, by, z, A, B, Cv, bias, resid,
                   K, lda, ldb, ldc, ldr, biasZ, sAz, sBz, sCz, sRz);
}

// ====== FUSED dispatch: WW-precompute (128 blocks) + G1 (1024 blocks) ======
// Shared 64KB LDS across both branches (passed into the body).
__global__ __launch_bounds__(256, 2)
void g1ww(const bf16* __restrict__ xb, const bf16* __restrict__ w1b,
          bf16* __restrict__ h1, const float* __restrict__ b1,
          const bf16* __restrict__ T4, bf16* __restrict__ WW)
{
  __shared__ __align__(16) bf16 lA[2 * 128 * 64];
  __shared__ __align__(16) bf16 lB[2 * 128 * 64];
  const int gb = blockIdx.x;
  if (gb < 128) {  // WW: z=0 WcT = wkT@wqT^T ; z=1 Wvo = wob@wvT^T (8,8,2)
    const int L = gb, xcd = L & 7, j = L >> 3;
    const int bx = j & 7, yy = xcd * 2 + (j >> 3);
    const int by = yy & 7, z = yy >> 3;
    gemm2s_body<EPI_PLAIN_BF16>(lA, lB, bx, by, z,
        T4 + (2 << 20), T4, WW, nullptr, nullptr,
        1024, 1024, 1024, 1024, 0, 0, 1 << 20, 1 << 20, 1 << 20, 0);
  } else {  // G1: h1 = relu(x @ w1^T + b1), sub-grid (16,64,1)
    const int L = gb - 128, xcd = L & 7, j = L >> 3;
    const int bx = j & 15, by = xcd * 8 + (j >> 4);
    gemm2s_body<EPI_BIAS_RELU>(lA, lB, bx, by, 0,
        xb, w1b, h1, b1, nullptr,
        1024, 1024, 1024, 2048, 0, 0, 0, 0, 0, 0);
  }
}

// ===== FUSED prep kernel (7936 blocks; matvecs first = latency overlap) =====
__global__ __launch_bounds__(256)
void cast_fused(const float* __restrict__ x,  const float* __restrict__ w1,
                const float* __restrict__ w2, const float* __restrict__ wq,
                const float* __restrict__ wk, const float* __restrict__ wv,
                const float* __restrict__ wo, const float* __restrict__ bq,
                const float* __restrict__ bv,
                bf16* __restrict__ xb, bf16* __restrict__ w1b,
                bf16* __restrict__ w2b, bf16* __restrict__ T4,
                float* __restrict__ bcbvo) {
  const int b = blockIdx.x, tid = threadIdx.x;
  if (b < 512) {  // matvecs: one wave per output
    const int wv_ = tid >> 6, ln = tid & 63;
    float acc = 0.f;
    if (b < 256) {
      const int e = b * 4 + wv_;
#pragma unroll
      for (int i = 0; i < 16; i++) {
        const int f = ln + i * 64;
        acc += bq[f] * 0.03125f * wk[(size_t)f * 1024 + e];
      }
      for (int o = 32; o; o >>= 1) acc += __shfl_xor(acc, o);
      if (ln == 0) bcbvo[e] = acc;
    } else {
      const int o = (b - 256) * 4 + wv_;
#pragma unroll
      for (int i = 0; i < 16; i++) {
        const int f = ln + i * 64;
        acc += wo[(size_t)o * 1024 + f] * bv[f];
      }
      for (int oo = 32; oo; oo >>= 1) acc += __shfl_xor(acc, oo);
      if (ln == 0) bcbvo[1024 + o] = acc;
    }
    return;
  }
  if (b < 7168) {  // straight casts
    const float* src; bf16* dst; int base;
    if (b < 4608)      { src = x;  dst = xb;        base = b - 512; }
    else if (b < 5632) { src = w1; dst = w1b;       base = b - 4608; }
    else if (b < 6656) { src = w2; dst = w2b;       base = b - 5632; }
    else               { src = wo; dst = T4 + (3 << 20); base = b - 6656; }
    const int i = base * 256 + tid;
    const float4* p = (const float4*)src;
    float4 a = p[2 * i], c = p[2 * i + 1];
    bf16x8 o8;
    o8[0] = (bf16)a.x; o8[1] = (bf16)a.y; o8[2] = (bf16)a.z; o8[3] = (bf16)a.w;
    o8[4] = (bf16)c.x; o8[5] = (bf16)c.y; o8[6] = (bf16)c.z; o8[7] = (bf16)c.w;
    ((bf16x8*)dst)[i] = o8;
    return;
  }
  // transpose-cast 64x64 tiles ([64][73] pad: 2-way max bank alias)
  __shared__ bf16 t[64][73];
  const float* src; bf16* dst; int tt; float scale = 1.f;
  if (b < 7424)      { src = wq; dst = T4;              tt = b - 7168; scale = 0.03125f; }
  else if (b < 7680) { src = wv; dst = T4 + (1 << 20);  tt = b - 7424; }
  else               { src = wk; dst = T4 + (2 << 20);  tt = b - 7680; }
  const int ty = tt >> 4, tx = tt & 15;
  const float* ib = src + (size_t)(ty * 64) * 1024 + tx * 64;
#pragma unroll
  for (int p = 0; p < 2; p++) {
    int r = p * 32 + tid / 8, cc = (tid % 8) * 8;
    float4 a = *(const float4*)(ib + (size_t)r * 1024 + cc);
    float4 d = *(const float4*)(ib + (size_t)r * 1024 + cc + 4);
    t[r][cc + 0] = (bf16)(a.x * scale); t[r][cc + 1] = (bf16)(a.y * scale);
    t[r][cc + 2] = (bf16)(a.z * scale); t[r][cc + 3] = (bf16)(a.w * scale);
    t[r][cc + 4] = (bf16)(d.x * scale); t[r][cc + 5] = (bf16)(d.y * scale);
    t[r][cc + 6] = (bf16)(d.z * scale); t[r][cc + 7] = (bf16)(d.w * scale);
  }
  __syncthreads();
#pragma unroll
  for (int p = 0; p < 2; p++) {
    int r = p * 32 + tid / 8, cc = (tid % 8) * 8;
    bf16x8 o;
#pragma unroll
    for (int j = 0; j < 8; j++) o[j] = t[cc + j][r];
    *(bf16x8*)(dst + (size_t)(tx * 64 + r) * 1024 + ty * 64 + cc) = o;
  }
}

// ===== FUSED softmax + g-transpose (10240 blocks) =====
__global__ __launch_bounds__(256)
void smT(bf16* __restrict__ S, const bf16* __restrict__ g,
         bf16* __restrict__ gT) {
  __shared__ float redm[4], reds[4];
  __shared__ bf16 t[64][73];
  const int b = blockIdx.x, tid = threadIdx.x;
  if (b < 8192) {
    const size_t row = b;
    const int wv_ = tid >> 6, ln = tid & 63;
    bf16x8 v8 = ((const bf16x8*)(S + row * 2048))[tid];
    float v[8];
#pragma unroll
    for (int j = 0; j < 8; j++) v[j] = (float)v8[j];
    float m = v[0];
#pragma unroll
    for (int j = 1; j < 8; j++) m = fmaxf(m, v[j]);
    for (int o = 32; o; o >>= 1) m = fmaxf(m, __shfl_xor(m, o));
    if (ln == 0) redm[wv_] = m;
    __syncthreads();
    m = fmaxf(fmaxf(redm[0], redm[1]), fmaxf(redm[2], redm[3]));
    float e[8], s = 0.f;
#pragma unroll
    for (int j = 0; j < 8; j++) { e[j] = __expf(v[j] - m); s += e[j]; }
    for (int o = 32; o; o >>= 1) s += __shfl_xor(s, o);
    if (ln == 0) reds[wv_] = s;
    __syncthreads();
    s = reds[0] + reds[1] + reds[2] + reds[3];
    const float inv = 1.f / s;
    bf16x8 o8;
#pragma unroll
    for (int j = 0; j < 8; j++) o8[j] = (bf16)(e[j] * inv);
    ((bf16x8*)(S + row * 2048))[tid] = o8;
    return;
  }
  const int tt = b - 8192;
  const int z = tt >> 9, rem = tt & 511;
  const int ty = rem >> 4, tx = rem & 15;
  const bf16* ib = g + (size_t)z * 2048 * 1024 + (size_t)(ty * 64) * 1024 + tx * 64;
  bf16* ob = gT + (size_t)z * 1024 * 2048;
#pragma unroll
  for (int p = 0; p < 2; p++) {
    int r = p * 32 + tid / 8, cc = (tid % 8) * 8;
    bf16x8 vv = *(const bf16x8*)(ib + (size_t)r * 1024 + cc);
#pragma unroll
    for (int j = 0; j < 8; j++) t[r][cc + j] = vv[j];
  }
  __syncthreads();
#pragma unroll
  for (int p = 0; p < 2; p++) {
    int r = p * 32 + tid / 8, cc = (tid % 8) * 8;
    bf16x8 o;
#pragma unroll
    for (int j = 0; j < 8; j++) o[j] = t[cc + j][r];
    *(bf16x8*)(ob + (size_t)(tx * 64 + r) * 2048 + ty * 64 + cc) = o;
  }
}

extern "C" void kernel_launch(void* const* d_in, const int* in_sizes, int n_in,
                              void* d_out, int out_size, void* d_ws, size_t ws_size,
                              hipStream_t stream) {
  const float* x  = (const float*)d_in[0];
  const float* w1 = (const float*)d_in[1];
  const float* b1 = (const float*)d_in[2];
  const float* w2 = (const float*)d_in[3];
  const float* b2 = (const float*)d_in[4];
  const float* wq = (const float*)d_in[5];
  const float* bq = (const float*)d_in[6];
  const float* wk = (const float*)d_in[7];
  const float* bk = (const float*)d_in[8];  // drops out: softmax row-invariant
  const float* wv = (const float*)d_in[9];
  const float* bv = (const float*)d_in[10];
  const float* wo = (const float*)d_in[11];
  const float* bo = (const float*)d_in[12];
  float* out = (float*)d_out;
  (void)bk;

  char* ws = (char*)d_ws;
  const size_t MB = 1024ull * 1024ull;
  if (ws_size < 130 * MB) return;

  bf16* w1b = (bf16*)(ws + 0 * MB);    // 4 MB
  bf16* w2b = (bf16*)(ws + 4 * MB);    // 4 MB
  bf16* T4  = (bf16*)(ws + 14 * MB);   // 8 MB: [wqT][wvT][wkT][wob]
  bf16* WW  = (bf16*)(ws + 22 * MB);   // 4 MB: [WcT][Wvo]
  float* bcbvo = (float*)(ws + 26 * MB);  // 8 KB: [bc 1024][bvo 1024]
  bf16* xb  = (bf16*)(ws + 27 * MB);   // 16 MB, dead after G1
  bf16* h1  = (bf16*)(ws + 43 * MB);   // 32 MB, dead after G2
  bf16* h   = (bf16*)(ws + 75 * MB);   // 16 MB, alive thru S'
  bf16* hq  = (bf16*)(ws + 91 * MB);   // 16 MB, dead after S'
  bf16* g   = (bf16*)(ws + 107 * MB);  // 16 MB, alive thru Pg (resid)
  bf16* S   = (bf16*)(ws + 43 * MB);   // 32 MB over dead h1 (softmax in-place)
  bf16* gT  = (bf16*)(ws + 27 * MB);   // 16 MB over dead xb

  // 1. fused prep: matvecs (front) + casts + weight transpose-casts
  cast_fused<<<7936, 256, 0, stream>>>(x, w1, w2, wq, wk, wv, wo, bq, bv,
                                       xb, w1b, w2b, T4, bcbvo);
  // 2. fused: WW precompute (128 blk) + G1 (1024 blk), SHARED 64KB LDS
  g1ww<<<1152, 256, 0, stream>>>(xb, w1b, h1, b1, T4, WW);
  // 3. G2: h = relu(h1 @ w2^T + b2)   M=8192 N=1024 K=2048
  gemm2s<EPI_BIAS_RELU><<<dim3(8, 64, 1), 256, 0, stream>>>(
      h1, w2b, h, b2, nullptr, 2048, 2048, 2048, 1024, 0, 0, 0, 0, 0, 0);
  // 4. z-batched: z=0 hq = h @ WcT^T + bc ; z=1 g = h @ Wvo^T + bvo
  gemm2s<EPI_BIAS_BF16><<<dim3(8, 64, 2), 256, 0, stream>>>(
      h, WW, hq, bcbvo, nullptr, 1024, 1024, 1024, 1024, 0, 1024,
      0, 1 << 20, 8LL << 20, 0);
  // 5. S' = hq @ h^T (z=4; differs from ref by softmax-invariant row const)
  gemm2s<EPI_PLAIN_BF16><<<dim3(16, 16, 4), 256, 0, stream>>>(
      hq, h, S, nullptr, nullptr, 1024, 1024, 1024, 2048, 0, 0,
      2048LL * 1024, 2048LL * 1024, 2048LL * 2048, 0);
  // 6. fused: P = softmax(S) in place  ∥  gT = transpose(g)
  smT<<<10240, 256, 0, stream>>>(S, g, gT);
  // 7. out = P @ gT^T + g + bo (f32)   M=2048 N=1024 K=2048, z=4
  gemm2s<EPI_RESID_BIAS_F32><<<dim3(8, 16, 4), 256, 0, stream>>>(
      S, gT, out, bo, g, 2048, 2048, 2048, 1024, 1024, 0,
      2048LL * 2048, 2048LL * 1024, 2048LL * 1024, 2048LL * 1024);
}

// Round 18
// 238.001 us; speedup vs baseline: 1.0648x; 1.0052x over previous
//
#include <hip/hip_runtime.h>
#include <hip/hip_bf16.h>

typedef __bf16 bf16;
typedef bf16 bf16x8 __attribute__((ext_vector_type(8)));
typedef float f32x4 __attribute__((ext_vector_type(4)));

#define EPI_BIAS_RELU      0
#define EPI_BIAS_BF16      1
#define EPI_PLAIN_BF16     2
#define EPI_RESID_BIAS_F32 3

__device__ __forceinline__ void lds_load16(const bf16* g, bf16* l) {
  __builtin_amdgcn_global_load_lds((__attribute__((address_space(1))) void*)g,
                                   (__attribute__((address_space(3))) void*)l,
                                   16, 0, 0);
}

template<int N> __device__ __forceinline__ void vmw() {
  if constexpr (N == 0) asm volatile("s_waitcnt vmcnt(0)" ::: "memory");
  else if constexpr (N == 4) asm volatile("s_waitcnt vmcnt(4)" ::: "memory");
}
__device__ __forceinline__ void barrier() { asm volatile("s_barrier" ::: "memory"); }

// Row-slab XCD mapping (r7-proven). Bijective when (gy*gz)%8==0 (all grids).
__device__ __forceinline__ void xcd_map(int& bx, int& by, int& z) {
  const int gx = gridDim.x, gy = gridDim.y;
  const int Y8 = (gy * gridDim.z) >> 3;
  const int L = (blockIdx.z * gy + blockIdx.y) * gx + blockIdx.x;
  const int xcd = L & 7, j = L >> 3;
  bx = j % gx;
  const int yy = xcd * Y8 + j / gx;
  by = yy % gy;
  z  = yy / gy;
}

// ====== 128x128 tile, BK=64, dbuf 64KB -> 2 blocks/CU (r11/r15-proven) ======
template<int EPI>
__global__ __launch_bounds__(256, 2)
void gemm2s(const bf16* __restrict__ A, const bf16* __restrict__ B,
            void* __restrict__ Cv, const float* __restrict__ bias,
            const bf16* __restrict__ resid,
            int K, int lda, int ldb, int ldc, int ldr, int biasZ,
            long long sAz, long long sBz, long long sCz, long long sRz)
{
  constexpr int BK = 64;
  constexpr int M_REP = 4, NH = 2;

  __shared__ __align__(16) bf16 lA[2][128 * BK];
  __shared__ __align__(16) bf16 lB[2][128 * BK];

  int bx, by, z;
  xcd_map(bx, by, z);

  const bf16* Ab = A + (size_t)z * sAz;
  const bf16* Bb = B + (size_t)z * sBz;
  const int row0 = by * 128, col0 = bx * 128;
  const int tid = threadIdx.x, w = tid >> 6, l = tid & 63;
  const int wr = w >> 1, wc = w & 1;

  const int srow = l >> 3, scb = (l & 7) ^ srow;
  const bf16* gA = Ab + (size_t)(row0 + w * 8 + srow) * lda + scb * 8;
  const bf16* gB = Bb + (size_t)(col0 + w * 8 + srow) * ldb + scb * 8;

  auto issueA = [&](int buf, int k0) {
#pragma unroll
    for (int i = 0; i < 4; i++)
      lds_load16(gA + (size_t)(i * 32) * lda + k0,
                 &lA[buf][(i * 32 + w * 8) * BK]);
  };
  auto issueB = [&](int buf, int k0) {
#pragma unroll
    for (int i = 0; i < 4; i++)
      lds_load16(gB + (size_t)(i * 32) * ldb + k0,
                 &lB[buf][(i * 32 + w * 8) * BK]);
  };

  const int fr = l & 15, fq = l >> 4, sw = fr & 7;
  bf16x8 aA[M_REP][2], bB0[NH][2], bB1[NH][2];
  f32x4 acc[M_REP][4] = {};

  auto readAfull = [&](int buf) {
#pragma unroll
    for (int m = 0; m < M_REP; m++) {
      const bf16* base = &lA[buf][(wr * 64 + m * 16 + fr) * BK];
#pragma unroll
      for (int kk = 0; kk < 2; kk++)
        aA[m][kk] = *(const bf16x8*)(base + ((kk * 4 + fq) ^ sw) * 8);
    }
  };
  auto readB = [&](bf16x8 (&dst)[NH][2], int buf, int h) {
#pragma unroll
    for (int nn = 0; nn < NH; nn++) {
      const bf16* base = &lB[buf][(wc * 64 + h * 32 + nn * 16 + fr) * BK];
#pragma unroll
      for (int kk = 0; kk < 2; kk++)
        dst[nn][kk] = *(const bf16x8*)(base + ((kk * 4 + fq) ^ sw) * 8);
    }
  };
  auto quad16 = [&](const bf16x8 (&b)[NH][2], int nBase) {
    __builtin_amdgcn_s_setprio(1);
#pragma unroll
    for (int kk = 0; kk < 2; kk++)
#pragma unroll
      for (int m = 0; m < M_REP; m++)
#pragma unroll
        for (int nh = 0; nh < NH; nh++)
          acc[m][nBase + nh] = __builtin_amdgcn_mfma_f32_16x16x32_bf16(
              aA[m][kk], b[nh][kk], acc[m][nBase + nh], 0, 0, 0);
    __builtin_amdgcn_s_setprio(0);
  };

  const int NT = K / BK;
  issueA(0, 0); issueB(0, 0); issueA(1, BK);
  vmw<4>();
  barrier();

  for (int t = 0; t < NT; t++) {
    const int cur = t & 1, nxt = cur ^ 1;
    const bool s1 = (t + 1 < NT), s2 = (t + 2 < NT);
    readAfull(cur);
    readB(bB0, cur, 0);
    if (s1) issueB(nxt, (t + 1) * BK);
    barrier();
    quad16(bB0, 0);
    barrier();
    readB(bB1, cur, 1);
    if (s2) { issueA(cur, (t + 2) * BK); vmw<4>(); }
    else vmw<0>();
    barrier();
    quad16(bB1, NH);
    barrier();
  }

  const float* bz = bias ? bias + (size_t)z * biasZ : nullptr;
#pragma unroll
  for (int m = 0; m < M_REP; m++) {
#pragma unroll
    for (int n = 0; n < 4; n++) {
      const int col = col0 + wc * 64 + n * 16 + fr;
#pragma unroll
      for (int j = 0; j < 4; j++) {
        const int rrow = row0 + wr * 64 + m * 16 + fq * 4 + j;
        const float val = acc[m][n][j];
        if constexpr (EPI == EPI_PLAIN_BF16) {
          bf16* Cp = (bf16*)Cv + (size_t)z * sCz;
          Cp[(size_t)rrow * ldc + col] = (bf16)val;
        } else if constexpr (EPI == EPI_BIAS_BF16) {
          bf16* Cp = (bf16*)Cv + (size_t)z * sCz;
          Cp[(size_t)rrow * ldc + col] = (bf16)(val + bz[col]);
        } else if constexpr (EPI == EPI_BIAS_RELU) {
          bf16* Cp = (bf16*)Cv;
          Cp[(size_t)rrow * ldc + col] = (bf16)fmaxf(val + bz[col], 0.f);
        } else {  // EPI_RESID_BIAS_F32: out = val + resid + bias (f32)
          float* Cp = (float*)Cv + (size_t)z * sCz;
          const bf16* Rp = resid + (size_t)z * sRz;
          Cp[(size_t)rrow * ldc + col] =
              val + (float)Rp[(size_t)rrow * ldr + col] + bz[col];
        }
      }
    }
  }
}

// ===== FUSED prep kernel (7936 blocks; matvecs first = latency overlap) =====
__global__ __launch_bounds__(256)
void cast_fused(const float* __restrict__ x,  const float* __restrict__ w1,
                const float* __restrict__ w2, const float* __restrict__ wq,
                const float* __restrict__ wk, const float* __restrict__ wv,
                const float* __restrict__ wo, const float* __restrict__ bq,
                const float* __restrict__ bv,
                bf16* __restrict__ xb, bf16* __restrict__ w1b,
                bf16* __restrict__ w2b, bf16* __restrict__ T4,
                float* __restrict__ bcbvo) {
  const int b = blockIdx.x, tid = threadIdx.x;
  if (b < 512) {  // matvecs: one wave per output, 16-step f-loop + reduce
    const int wv_ = tid >> 6, ln = tid & 63;
    float acc = 0.f;
    if (b < 256) {
      const int e = b * 4 + wv_;
#pragma unroll
      for (int i = 0; i < 16; i++) {
        const int f = ln + i * 64;
        acc += bq[f] * 0.03125f * wk[(size_t)f * 1024 + e];
      }
      for (int o = 32; o; o >>= 1) acc += __shfl_xor(acc, o);
      if (ln == 0) bcbvo[e] = acc;
    } else {
      const int o = (b - 256) * 4 + wv_;
#pragma unroll
      for (int i = 0; i < 16; i++) {
        const int f = ln + i * 64;
        acc += wo[(size_t)o * 1024 + f] * bv[f];
      }
      for (int oo = 32; oo; oo >>= 1) acc += __shfl_xor(acc, oo);
      if (ln == 0) bcbvo[1024 + o] = acc;
    }
    return;
  }
  if (b < 7168) {  // straight casts
    const float* src; bf16* dst; int base;
    if (b < 4608)      { src = x;  dst = xb;        base = b - 512; }
    else if (b < 5632) { src = w1; dst = w1b;       base = b - 4608; }
    else if (b < 6656) { src = w2; dst = w2b;       base = b - 5632; }
    else               { src = wo; dst = T4 + (3 << 20); base = b - 6656; }
    const int i = base * 256 + tid;
    const float4* p = (const float4*)src;
    float4 a = p[2 * i], c = p[2 * i + 1];
    bf16x8 o8;
    o8[0] = (bf16)a.x; o8[1] = (bf16)a.y; o8[2] = (bf16)a.z; o8[3] = (bf16)a.w;
    o8[4] = (bf16)c.x; o8[5] = (bf16)c.y; o8[6] = (bf16)c.z; o8[7] = (bf16)c.w;
    ((bf16x8*)dst)[i] = o8;
    return;
  }
  // transpose-cast 64x64 tiles of a 1024x1024 f32 matrix ([64][73]: 2-way max)
  __shared__ bf16 t[64][73];
  const float* src; bf16* dst; int tt; float scale = 1.f;
  if (b < 7424)      { src = wq; dst = T4;              tt = b - 7168; scale = 0.03125f; }
  else if (b < 7680) { src = wv; dst = T4 + (1 << 20);  tt = b - 7424; }
  else               { src = wk; dst = T4 + (2 << 20);  tt = b - 7680; }
  const int ty = tt >> 4, tx = tt & 15;
  const float* ib = src + (size_t)(ty * 64) * 1024 + tx * 64;
#pragma unroll
  for (int p = 0; p < 2; p++) {
    int r = p * 32 + tid / 8, cc = (tid % 8) * 8;
    float4 a = *(const float4*)(ib + (size_t)r * 1024 + cc);
    float4 d = *(const float4*)(ib + (size_t)r * 1024 + cc + 4);
    t[r][cc + 0] = (bf16)(a.x * scale); t[r][cc + 1] = (bf16)(a.y * scale);
    t[r][cc + 2] = (bf16)(a.z * scale); t[r][cc + 3] = (bf16)(a.w * scale);
    t[r][cc + 4] = (bf16)(d.x * scale); t[r][cc + 5] = (bf16)(d.y * scale);
    t[r][cc + 6] = (bf16)(d.z * scale); t[r][cc + 7] = (bf16)(d.w * scale);
  }
  __syncthreads();
#pragma unroll
  for (int p = 0; p < 2; p++) {
    int r = p * 32 + tid / 8, cc = (tid % 8) * 8;
    bf16x8 o;
#pragma unroll
    for (int j = 0; j < 8; j++) o[j] = t[cc + j][r];
    *(bf16x8*)(dst + (size_t)(tx * 64 + r) * 1024 + ty * 64 + cc) = o;
  }
}

// ===== FUSED softmax + g-transpose (block-range, 10240 blocks):
//  [0,8192)      row softmax of S in place (rows of 2048 bf16)
//  [8192,10240)  transpose g (z=4, 2048x1024 each) -> gT (1024x2048)
__global__ __launch_bounds__(256)
void smT(bf16* __restrict__ S, const bf16* __restrict__ g,
         bf16* __restrict__ gT) {
  __shared__ float redm[4], reds[4];
  __shared__ bf16 t[64][73];
  const int b = blockIdx.x, tid = threadIdx.x;
  if (b < 8192) {
    const size_t row = b;
    const int wv_ = tid >> 6, ln = tid & 63;
    bf16x8 v8 = ((const bf16x8*)(S + row * 2048))[tid];
    float v[8];
#pragma unroll
    for (int j = 0; j < 8; j++) v[j] = (float)v8[j];
    float m = v[0];
#pragma unroll
    for (int j = 1; j < 8; j++) m = fmaxf(m, v[j]);
    for (int o = 32; o; o >>= 1) m = fmaxf(m, __shfl_xor(m, o));
    if (ln == 0) redm[wv_] = m;
    __syncthreads();
    m = fmaxf(fmaxf(redm[0], redm[1]), fmaxf(redm[2], redm[3]));
    float e[8], s = 0.f;
#pragma unroll
    for (int j = 0; j < 8; j++) { e[j] = __expf(v[j] - m); s += e[j]; }
    for (int o = 32; o; o >>= 1) s += __shfl_xor(s, o);
    if (ln == 0) reds[wv_] = s;
    __syncthreads();
    s = reds[0] + reds[1] + reds[2] + reds[3];
    const float inv = 1.f / s;
    bf16x8 o8;
#pragma unroll
    for (int j = 0; j < 8; j++) o8[j] = (bf16)(e[j] * inv);
    ((bf16x8*)(S + row * 2048))[tid] = o8;
    return;
  }
  // g transpose: per batch z, 32 row-tiles x 16 col-tiles of 64x64
  const int tt = b - 8192;
  const int z = tt >> 9, rem = tt & 511;
  const int ty = rem >> 4, tx = rem & 15;
  const bf16* ib = g + (size_t)z * 2048 * 1024 + (size_t)(ty * 64) * 1024 + tx * 64;
  bf16* ob = gT + (size_t)z * 1024 * 2048;
#pragma unroll
  for (int p = 0; p < 2; p++) {
    int r = p * 32 + tid / 8, cc = (tid % 8) * 8;
    bf16x8 vv = *(const bf16x8*)(ib + (size_t)r * 1024 + cc);
#pragma unroll
    for (int j = 0; j < 8; j++) t[r][cc + j] = vv[j];
  }
  __syncthreads();
#pragma unroll
  for (int p = 0; p < 2; p++) {
    int r = p * 32 + tid / 8, cc = (tid % 8) * 8;
    bf16x8 o;
#pragma unroll
    for (int j = 0; j < 8; j++) o[j] = t[cc + j][r];
    *(bf16x8*)(ob + (size_t)(tx * 64 + r) * 2048 + ty * 64 + cc) = o;
  }
}

extern "C" void kernel_launch(void* const* d_in, const int* in_sizes, int n_in,
                              void* d_out, int out_size, void* d_ws, size_t ws_size,
                              hipStream_t stream) {
  const float* x  = (const float*)d_in[0];
  const float* w1 = (const float*)d_in[1];
  const float* b1 = (const float*)d_in[2];
  const float* w2 = (const float*)d_in[3];
  const float* b2 = (const float*)d_in[4];
  const float* wq = (const float*)d_in[5];
  const float* bq = (const float*)d_in[6];
  const float* wk = (const float*)d_in[7];
  const float* bk = (const float*)d_in[8];  // drops out: softmax row-invariant
  const float* wv = (const float*)d_in[9];
  const float* bv = (const float*)d_in[10];
  const float* wo = (const float*)d_in[11];
  const float* bo = (const float*)d_in[12];
  float* out = (float*)d_out;
  (void)bk;

  char* ws = (char*)d_ws;
  const size_t MB = 1024ull * 1024ull;
  if (ws_size < 130 * MB) return;

  bf16* w1b = (bf16*)(ws + 0 * MB);    // 4 MB
  bf16* w2b = (bf16*)(ws + 4 * MB);    // 4 MB
  bf16* T4  = (bf16*)(ws + 14 * MB);   // 8 MB: [wqT][wvT][wkT][wob]
  bf16* WW  = (bf16*)(ws + 22 * MB);   // 4 MB: [WcT][Wvo]
  float* bcbvo = (float*)(ws + 26 * MB);  // 8 KB: [bc 1024][bvo 1024]
  bf16* xb  = (bf16*)(ws + 27 * MB);   // 16 MB, dead after G1
  bf16* h1  = (bf16*)(ws + 43 * MB);   // 32 MB, dead after G2
  bf16* h   = (bf16*)(ws + 75 * MB);   // 16 MB, alive thru S'
  bf16* hq  = (bf16*)(ws + 91 * MB);   // 16 MB, dead after S'
  bf16* g   = (bf16*)(ws + 107 * MB);  // 16 MB, alive thru Pg (resid)
  bf16* S   = (bf16*)(ws + 43 * MB);   // 32 MB over dead h1 (softmax in-place)
  bf16* gT  = (bf16*)(ws + 27 * MB);   // 16 MB over dead xb

  // 1. fused prep: matvecs (front) + casts + weight transpose-casts
  cast_fused<<<7936, 256, 0, stream>>>(x, w1, w2, wq, wk, wv, wo, bq, bv,
                                       xb, w1b, w2b, T4, bcbvo);
  // 2. z-batched precompute: z=0 WcT = wkT @ wqT^T ; z=1 Wvo = wob @ wvT^T
  gemm2s<EPI_PLAIN_BF16><<<dim3(8, 8, 2), 256, 0, stream>>>(
      T4 + (2 << 20), T4, WW, nullptr, nullptr,
      1024, 1024, 1024, 1024, 0, 0, 1 << 20, 1 << 20, 1 << 20, 0);
  // 3. G1: h1 = relu(x @ w1^T + b1)   M=8192 N=2048 K=1024
  gemm2s<EPI_BIAS_RELU><<<dim3(16, 64, 1), 256, 0, stream>>>(
      xb, w1b, h1, b1, nullptr, 1024, 1024, 1024, 2048, 0, 0, 0, 0, 0, 0);
  // 4. G2: h = relu(h1 @ w2^T + b2)   M=8192 N=1024 K=2048
  gemm2s<EPI_BIAS_RELU><<<dim3(8, 64, 1), 256, 0, stream>>>(
      h1, w2b, h, b2, nullptr, 2048, 2048, 2048, 1024, 0, 0, 0, 0, 0, 0);
  // 5. z-batched: z=0 hq = h @ WcT^T + bc ; z=1 g = h @ Wvo^T + bvo
  gemm2s<EPI_BIAS_BF16><<<dim3(8, 64, 2), 256, 0, stream>>>(
      h, WW, hq, bcbvo, nullptr, 1024, 1024, 1024, 1024, 0, 1024,
      0, 1 << 20, 8LL << 20, 0);
  // 6. S' = hq @ h^T (z=4; differs from ref by softmax-invariant row const)
  gemm2s<EPI_PLAIN_BF16><<<dim3(16, 16, 4), 256, 0, stream>>>(
      hq, h, S, nullptr, nullptr, 1024, 1024, 1024, 2048, 0, 0,
      2048LL * 1024, 2048LL * 1024, 2048LL * 2048, 0);
  // 7. fused: P = softmax(S) in place  ∥  gT = transpose(g)
  smT<<<10240, 256, 0, stream>>>(S, g, gT);
  // 8. out = P @ gT^T + g + bo (f32)   M=2048 N=1024 K=2048, z=4
  gemm2s<EPI_RESID_BIAS_F32><<<dim3(8, 16, 4), 256, 0, stream>>>(
      S, gT, out, bo, g, 2048, 2048, 2048, 1024, 1024, 0,
      2048LL * 2048, 2048LL * 1024, 2048LL * 1024, 2048LL * 1024);
}